// Round 7
// baseline (20.196 us; speedup 1.0000x reference)
//
#include <hip/hip_runtime.h>

// Geometry:
//   x : (1,24,56,56) f32  -> c*3136 + h*56 + w
//   w1: (96,3,21)    f32  -> i*63 + j*21 + k
//   w2: (12,7,21)    f32  -> c*147 + jj*21 + k
//   y : (1,96,56,56) f32  -> i*3136 + h*56 + w
//
// t3r[c,h,w] = x[c,h,(w-1)%56] + x[c+12,h,(w-1)%56]          (roll +1 width)
// t5[h,w,k]  = sum_{c<12,jj<7} t3r[c,h,w+jj-3] * w2[c,jj,k]   (zero width-pad)
// y[i,h,w]   = sum_{j<3,k<21}  t5[h+j-1,w,k]  * w1[i,j,k]     (zero height-pad)
//
// R6: 112 blocks (56 h x 2 i-chunks of 48) x 512 thr = 8 waves = 2/SIMD on
// 112 CUs. R5 showed 1 wave/SIMD exposes all latency; R4 showed 4/SIMD on
// 56 CUs is issue-crowded. Stage 1 uses a flat (r,k)-pair split: 63 pairs,
// 8/wave with wraparound -> perfectly balanced 672 FMA/wave. Pair 0 is
// computed by waves 0 and 7 with the same FMA order -> bit-identical write.

#define NH 56
#define NW 56
#define NC 12
#define NK 21
#define NI 96
#define ICHUNK 48

__global__ __launch_bounds__(512)
void fused_kernel(const float* __restrict__ x,
                  const float* __restrict__ w1,
                  const float* __restrict__ w2,
                  float* __restrict__ y) {
    __shared__ float s_t3[3][NC][NW + 6];   // 2232 f32, 8.9 KB (p <-> ww = p-3)
    __shared__ float s_t5[3][NW * NK];      // 3528 f32, 14.1 KB

    const int h    = blockIdx.x;
    const int i0   = blockIdx.y * ICHUNK;
    const int tid  = threadIdx.x;
    const int wid  = tid >> 6;
    const int lane = tid & 63;

    // --- stage t3 rows h-1..h+1 (pair-sum + width-roll, zero-pad h and w) ---
    for (int e = tid; e < 3 * NC * (NW + 6); e += 512) {
        const int r = e / (NC * (NW + 6));
        const int c = (e / (NW + 6)) % NC;
        const int p = e % (NW + 6);
        const int hh = h - 1 + r;
        const int ww = p - 3;
        float v = 0.0f;
        if (hh >= 0 && hh < NH && ww >= 0 && ww < NW) {
            const int wsrc = (ww + NW - 1) % NW;   // roll(+1): out[w] = in[w-1]
            const int base = hh * NW + wsrc;
            v = x[c * 3136 + base] + x[(c + 12) * 3136 + base];
        }
        s_t3[r][c][p] = v;
    }
    __syncthreads();

    // --- stage 1: 63 (r,k) pairs; wave wid -> pairs [8*wid, 8*wid+8) mod 63 ---
    if (lane < NW) {
        const int w = lane;
        int p = __builtin_amdgcn_readfirstlane(wid * 8);   // scalar loop state
        int remaining = 8;
        while (remaining > 0) {
            if (p >= 63) p -= 63;
            const int r  = p / 21;                 // scalar magic-mul div
            const int kb = p % 21;
            const int nk = remaining < (21 - kb) ? remaining : (21 - kb);
            float acc[8] = {0.f, 0.f, 0.f, 0.f, 0.f, 0.f, 0.f, 0.f};
            for (int c = 0; c < NC; ++c) {
                float win[7];
                #pragma unroll
                for (int jj = 0; jj < 7; ++jj) win[jj] = s_t3[r][c][w + jj];
                const float* __restrict__ wp = w2 + c * 147 + kb;  // SGPR base
                #pragma unroll
                for (int kk = 0; kk < 8; ++kk) {
                    if (kk < nk) {                 // uniform predicate -> s_cbranch
                        float a = acc[kk];
                        #pragma unroll
                        for (int jj = 0; jj < 7; ++jj) a += win[jj] * wp[jj * NK + kk];
                        acc[kk] = a;
                    }
                }
            }
            #pragma unroll
            for (int kk = 0; kk < 8; ++kk) {
                if (kk < nk) s_t5[r][w * NK + kb + kk] = acc[kk];
            }
            p += nk;
            remaining -= nk;
        }
    }
    __syncthreads();

    // --- stage 2: wave wid -> 6 output channels of this block's 48 ---
    if (lane < NW) {
        const int w = lane;
        float v[3][NK];
        #pragma unroll
        for (int j = 0; j < 3; ++j) {
            #pragma unroll
            for (int k = 0; k < NK; ++k) v[j][k] = s_t5[j][w * NK + k];
        }
        const int ibase = __builtin_amdgcn_readfirstlane(i0 + wid * 6);
        #pragma unroll
        for (int il = 0; il < 6; ++il) {
            const int i = ibase + il;
            const float* __restrict__ wp = w1 + i * 63;            // SGPR base
            float acc = 0.0f;
            #pragma unroll
            for (int j = 0; j < 3; ++j) {
                #pragma unroll
                for (int k = 0; k < NK; ++k) acc += v[j][k] * wp[j * NK + k];
            }
            y[i * 3136 + h * NW + w] = acc;
        }
    }
}

extern "C" void kernel_launch(void* const* d_in, const int* in_sizes, int n_in,
                              void* d_out, int out_size, void* d_ws, size_t ws_size,
                              hipStream_t stream) {
    const float* x  = (const float*)d_in[0];
    const float* w1 = (const float*)d_in[1];
    const float* w2 = (const float*)d_in[2];
    float* y = (float*)d_out;
    fused_kernel<<<dim3(NH, NI / ICHUNK), dim3(512), 0, stream>>>(x, w1, w2, y);
}

// Round 8
// 13.498 us; speedup vs baseline: 1.4962x; 1.4962x over previous
//
#include <hip/hip_runtime.h>

// Geometry:
//   x : (1,24,56,56) f32  -> c*3136 + h*56 + w
//   w1: (96,3,21)    f32  -> i*63 + j*21 + k
//   w2: (12,7,21)    f32  -> c*147 + jj*21 + k
//   y : (1,96,56,56) f32  -> i*3136 + h*56 + w
//
// t3r[c,h,w] = x[c,h,(w-1)%56] + x[c+12,h,(w-1)%56]          (roll +1 width)
// t5[h,w,k]  = sum_{c<12,jj<7} t3r[c,h,w+jj-3] * w2[c,jj,k]   (zero width-pad)
// y[i,h,w]   = sum_{j<3,k<21}  t5[h+j-1,w,k]  * w1[i,j,k]     (zero height-pad)
//
// R7: keep R4's winning ingredient (16 waves/block = 4/SIMD for latency
// hiding) but balance and shrink per-SIMD issue:
//   - grid 112 blocks (56 h x 2 i-chunks of 48) x 1024 thr, 1 block/CU
//   - stage 1 = 12 tasks (3 rows x 4 k-groups {6,5,5,5}) -> every SIMD
//     gets exactly 3 tasks (~2690 cyc issue vs R4's worst-SIMD 3528)
//   - stage 2 = 3 channels/wave (1512 cyc/SIMD vs R4's 3024)

#define NH 56
#define NW 56
#define NC 12
#define NK 21
#define NI 96
#define ICHUNK 48

__global__ __launch_bounds__(1024)
void fused_kernel(const float* __restrict__ x,
                  const float* __restrict__ w1,
                  const float* __restrict__ w2,
                  float* __restrict__ y) {
    __shared__ float s_t3[3][NC][NW + 6];   // 2232 f32, 8.9 KB (p <-> ww = p-3)
    __shared__ float s_t5[3][NW * NK];      // 3528 f32, 14.1 KB

    const int h    = blockIdx.x;
    const int i0   = blockIdx.y * ICHUNK;
    const int tid  = threadIdx.x;
    const int wid  = tid >> 6;
    const int lane = tid & 63;

    // --- stage t3 rows h-1..h+1 (pair-sum + width-roll, zero-pad h and w) ---
    for (int e = tid; e < 3 * NC * (NW + 6); e += 1024) {
        const int r = e / (NC * (NW + 6));
        const int c = (e / (NW + 6)) % NC;
        const int p = e % (NW + 6);
        const int hh = h - 1 + r;
        const int ww = p - 3;
        float v = 0.0f;
        if (hh >= 0 && hh < NH && ww >= 0 && ww < NW) {
            const int wsrc = (ww + NW - 1) % NW;   // roll(+1): out[w] = in[w-1]
            const int base = hh * NW + wsrc;
            v = x[c * 3136 + base] + x[(c + 12) * 3136 + base];
        }
        s_t3[r][c][p] = v;
    }
    __syncthreads();

    // --- stage 1: 12 tasks; wave wid<12 -> (r = wid>>2, kgroup = wid&3) ---
    // k-group starts {0,6,11,16}, sizes {6,5,5,5}. Waves 12..15 idle here.
    if (wid < 12 && lane < NW) {
        const int w  = lane;
        const int r  = wid >> 2;
        const int kg = wid & 3;
        const int k0 = __builtin_amdgcn_readfirstlane(kg * 5 + (kg ? 1 : 0));
        const int nk = kg ? 5 : 6;
        float acc[6] = {0.f, 0.f, 0.f, 0.f, 0.f, 0.f};
        for (int c = 0; c < NC; ++c) {
            float win[7];
            #pragma unroll
            for (int jj = 0; jj < 7; ++jj) win[jj] = s_t3[r][c][w + jj];
            const float* __restrict__ wp = w2 + c * 147 + k0;   // SGPR base
            #pragma unroll
            for (int kk = 0; kk < 6; ++kk) {
                if (kk < nk) {                     // uniform -> scalar branch
                    float a = acc[kk];
                    #pragma unroll
                    for (int jj = 0; jj < 7; ++jj) a += win[jj] * wp[jj * NK + kk];
                    acc[kk] = a;
                }
            }
        }
        #pragma unroll
        for (int kk = 0; kk < 6; ++kk) {
            if (kk < nk) s_t5[r][w * NK + k0 + kk] = acc[kk];
        }
    }
    __syncthreads();

    // --- stage 2: wave wid -> 3 output channels of this block's 48 ---
    if (lane < NW) {
        const int w = lane;
        float v[3][NK];
        #pragma unroll
        for (int j = 0; j < 3; ++j) {
            #pragma unroll
            for (int k = 0; k < NK; ++k) v[j][k] = s_t5[j][w * NK + k];
        }
        const int ibase = __builtin_amdgcn_readfirstlane(i0 + wid * 3);
        #pragma unroll
        for (int il = 0; il < 3; ++il) {
            const int i = ibase + il;
            const float* __restrict__ wp = w1 + i * 63;             // SGPR base
            float acc = 0.0f;
            #pragma unroll
            for (int j = 0; j < 3; ++j) {
                #pragma unroll
                for (int k = 0; k < NK; ++k) acc += v[j][k] * wp[j * NK + k];
            }
            y[i * 3136 + h * NW + w] = acc;
        }
    }
}

extern "C" void kernel_launch(void* const* d_in, const int* in_sizes, int n_in,
                              void* d_out, int out_size, void* d_ws, size_t ws_size,
                              hipStream_t stream) {
    const float* x  = (const float*)d_in[0];
    const float* w1 = (const float*)d_in[1];
    const float* w2 = (const float*)d_in[2];
    float* y = (float*)d_out;
    fused_kernel<<<dim3(NH, NI / ICHUNK), dim3(1024), 0, stream>>>(x, w1, w2, y);
}

// Round 9
// 12.428 us; speedup vs baseline: 1.6250x; 1.0861x over previous
//
#include <hip/hip_runtime.h>

// Geometry:
//   x : (1,24,56,56) f32  -> c*3136 + h*56 + w
//   w1: (96,3,21)    f32  -> i*63 + j*21 + k
//   w2: (12,7,21)    f32  -> c*147 + jj*21 + k
//   y : (1,96,56,56) f32  -> i*3136 + h*56 + w
//
// t3r[c,h,w] = x[c,h,(w-1)%56] + x[c+12,h,(w-1)%56]          (roll +1 width)
// t5[h,w,k]  = sum_{c<12,jj<7} t3r[c,h,w+jj-3] * w2[c,jj,k]   (zero width-pad)
// y[i,h,w]   = sum_{j<3,k<21}  t5[h+j-1,w,k]  * w1[i,j,k]     (zero height-pad)
//
// R8: 224 blocks (56 h x 4 i-chunks of 24) x 1024 thr = 16 waves = 4/SIMD
// (R4/R7's proven latency-hiding point) on 224 CUs. Stage 1 unchanged from
// R7 (12 balanced tasks: 3 rows x 4 k-groups {6,5,5,5} -> 3 tasks/SIMD).
// Stage 2 shrinks to 6 ch/SIMD: waves 0..7 take 2 channels, 8..15 take 1.

#define NH 56
#define NW 56
#define NC 12
#define NK 21
#define NI 96
#define ICHUNK 24

__global__ __launch_bounds__(1024)
void fused_kernel(const float* __restrict__ x,
                  const float* __restrict__ w1,
                  const float* __restrict__ w2,
                  float* __restrict__ y) {
    __shared__ float s_t3[3][NC][NW + 6];   // 2232 f32, 8.9 KB (p <-> ww = p-3)
    __shared__ float s_t5[3][NW * NK];      // 3528 f32, 14.1 KB

    const int h    = blockIdx.x;
    const int i0   = blockIdx.y * ICHUNK;
    const int tid  = threadIdx.x;
    const int wid  = tid >> 6;
    const int lane = tid & 63;

    // --- stage t3 rows h-1..h+1 (pair-sum + width-roll, zero-pad h and w) ---
    for (int e = tid; e < 3 * NC * (NW + 6); e += 1024) {
        const int r = e / (NC * (NW + 6));
        const int c = (e / (NW + 6)) % NC;
        const int p = e % (NW + 6);
        const int hh = h - 1 + r;
        const int ww = p - 3;
        float v = 0.0f;
        if (hh >= 0 && hh < NH && ww >= 0 && ww < NW) {
            const int wsrc = (ww + NW - 1) % NW;   // roll(+1): out[w] = in[w-1]
            const int base = hh * NW + wsrc;
            v = x[c * 3136 + base] + x[(c + 12) * 3136 + base];
        }
        s_t3[r][c][p] = v;
    }
    __syncthreads();

    // --- stage 1: 12 tasks; wave wid<12 -> (r = wid>>2, kgroup = wid&3) ---
    // k-group starts {0,6,11,16}, sizes {6,5,5,5}. Waves 12..15 idle here.
    if (wid < 12 && lane < NW) {
        const int w  = lane;
        const int r  = wid >> 2;
        const int kg = wid & 3;
        const int k0 = __builtin_amdgcn_readfirstlane(kg * 5 + (kg ? 1 : 0));
        const int nk = kg ? 5 : 6;
        float acc[6] = {0.f, 0.f, 0.f, 0.f, 0.f, 0.f};
        for (int c = 0; c < NC; ++c) {
            float win[7];
            #pragma unroll
            for (int jj = 0; jj < 7; ++jj) win[jj] = s_t3[r][c][w + jj];
            const float* __restrict__ wp = w2 + c * 147 + k0;   // SGPR base
            #pragma unroll
            for (int kk = 0; kk < 6; ++kk) {
                if (kk < nk) {                     // uniform -> scalar branch
                    float a = acc[kk];
                    #pragma unroll
                    for (int jj = 0; jj < 7; ++jj) a += win[jj] * wp[jj * NK + kk];
                    acc[kk] = a;
                }
            }
        }
        #pragma unroll
        for (int kk = 0; kk < 6; ++kk) {
            if (kk < nk) s_t5[r][w * NK + k0 + kk] = acc[kk];
        }
    }
    __syncthreads();

    // --- stage 2: channels wid, wid+16 (if present) of this block's 24 ---
    if (lane < NW) {
        const int w = lane;
        float v[3][NK];
        #pragma unroll
        for (int j = 0; j < 3; ++j) {
            #pragma unroll
            for (int k = 0; k < NK; ++k) v[j][k] = s_t5[j][w * NK + k];
        }
        for (int t = wid; t < ICHUNK; t += 16) {   // wave-uniform trip count
            const int i = __builtin_amdgcn_readfirstlane(i0 + t);
            const float* __restrict__ wp = w1 + i * 63;             // SGPR base
            float acc = 0.0f;
            #pragma unroll
            for (int j = 0; j < 3; ++j) {
                #pragma unroll
                for (int k = 0; k < NK; ++k) acc += v[j][k] * wp[j * NK + k];
            }
            y[i * 3136 + h * NW + w] = acc;
        }
    }
}

extern "C" void kernel_launch(void* const* d_in, const int* in_sizes, int n_in,
                              void* d_out, int out_size, void* d_ws, size_t ws_size,
                              hipStream_t stream) {
    const float* x  = (const float*)d_in[0];
    const float* w1 = (const float*)d_in[1];
    const float* w2 = (const float*)d_in[2];
    float* y = (float*)d_out;
    fused_kernel<<<dim3(NH, NI / ICHUNK), dim3(1024), 0, stream>>>(x, w1, w2, y);
}

// Round 10
// 12.280 us; speedup vs baseline: 1.6446x; 1.0120x over previous
//
#include <hip/hip_runtime.h>

// Geometry:
//   x : (1,24,56,56) f32  -> c*3136 + h*56 + w
//   w1: (96,3,21)    f32  -> i*63 + j*21 + k
//   w2: (12,7,21)    f32  -> c*147 + jj*21 + k
//   y : (1,96,56,56) f32  -> i*3136 + h*56 + w
//
// t3r[c,h,w] = x[c,h,(w-1)%56] + x[c+12,h,(w-1)%56]          (roll +1 width)
// t5[h,w,k]  = sum_{c<12,jj<7} t3r[c,h,w+jj-3] * w2[c,jj,k]   (zero width-pad)
// y[i,h,w]   = sum_{j<3,k<21}  t5[h+j-1,w,k]  * w1[i,j,k]     (zero height-pad)
//
// R9 = R8 + SIMD-balanced stage-1 task map. 224 blocks (56 h x 4 i-chunks
// of 24) x 1024 thr = 16 waves = 4/SIMD on 224 CUs. Stage-1 tasks
// (r, kgroup) with kg widths {6,5,5,5}: R8 mapped wid 0,4,8 all to kg=0,
// putting all three 6-wide tasks on SIMD 0 (18 k-units = 3024 issue-cyc
// vs 15 = 2520 elsewhere). Rotation kg=(a+s)&3 (a=wid>>2, s=wid&3) caps
// every SIMD at 16 units (2688 cyc): s0:{6,5,5} s1:{5,5,5} s2:{5,5,6}
// s3:{5,6,5}.

#define NH 56
#define NW 56
#define NC 12
#define NK 21
#define NI 96
#define ICHUNK 24

__global__ __launch_bounds__(1024)
void fused_kernel(const float* __restrict__ x,
                  const float* __restrict__ w1,
                  const float* __restrict__ w2,
                  float* __restrict__ y) {
    __shared__ float s_t3[3][NC][NW + 6];   // 2232 f32, 8.9 KB (p <-> ww = p-3)
    __shared__ float s_t5[3][NW * NK];      // 3528 f32, 14.1 KB

    const int h    = blockIdx.x;
    const int i0   = blockIdx.y * ICHUNK;
    const int tid  = threadIdx.x;
    const int wid  = tid >> 6;
    const int lane = tid & 63;

    // --- stage t3 rows h-1..h+1 (pair-sum + width-roll, zero-pad h and w) ---
    for (int e = tid; e < 3 * NC * (NW + 6); e += 1024) {
        const int r = e / (NC * (NW + 6));
        const int c = (e / (NW + 6)) % NC;
        const int p = e % (NW + 6);
        const int hh = h - 1 + r;
        const int ww = p - 3;
        float v = 0.0f;
        if (hh >= 0 && hh < NH && ww >= 0 && ww < NW) {
            const int wsrc = (ww + NW - 1) % NW;   // roll(+1): out[w] = in[w-1]
            const int base = hh * NW + wsrc;
            v = x[c * 3136 + base] + x[(c + 12) * 3136 + base];
        }
        s_t3[r][c][p] = v;
    }
    __syncthreads();

    // --- stage 1: 12 tasks; wid<12 -> r = wid>>2, kg = ((wid>>2)+(wid&3))&3 ---
    // k-group starts {0,6,11,16}, sizes {6,5,5,5}; rotation balances SIMDs.
    if (wid < 12 && lane < NW) {
        const int w  = lane;
        const int a  = wid >> 2;
        const int r  = a;
        const int kg = (a + (wid & 3)) & 3;
        const int k0 = __builtin_amdgcn_readfirstlane(kg * 5 + (kg ? 1 : 0));
        const int nk = kg ? 5 : 6;
        float acc[6] = {0.f, 0.f, 0.f, 0.f, 0.f, 0.f};
        for (int c = 0; c < NC; ++c) {
            float win[7];
            #pragma unroll
            for (int jj = 0; jj < 7; ++jj) win[jj] = s_t3[r][c][w + jj];
            const float* __restrict__ wp = w2 + c * 147 + k0;   // SGPR base
            #pragma unroll
            for (int kk = 0; kk < 6; ++kk) {
                if (kk < nk) {                     // uniform -> scalar branch
                    float a2 = acc[kk];
                    #pragma unroll
                    for (int jj = 0; jj < 7; ++jj) a2 += win[jj] * wp[jj * NK + kk];
                    acc[kk] = a2;
                }
            }
        }
        #pragma unroll
        for (int kk = 0; kk < 6; ++kk) {
            if (kk < nk) s_t5[r][w * NK + k0 + kk] = acc[kk];
        }
    }
    __syncthreads();

    // --- stage 2: channels wid, wid+16 (if present) of this block's 24 ---
    if (lane < NW) {
        const int w = lane;
        float v[3][NK];
        #pragma unroll
        for (int j = 0; j < 3; ++j) {
            #pragma unroll
            for (int k = 0; k < NK; ++k) v[j][k] = s_t5[j][w * NK + k];
        }
        for (int t = wid; t < ICHUNK; t += 16) {   // wave-uniform trip count
            const int i = __builtin_amdgcn_readfirstlane(i0 + t);
            const float* __restrict__ wp = w1 + i * 63;             // SGPR base
            float acc = 0.0f;
            #pragma unroll
            for (int j = 0; j < 3; ++j) {
                #pragma unroll
                for (int k = 0; k < NK; ++k) acc += v[j][k] * wp[j * NK + k];
            }
            y[i * 3136 + h * NW + w] = acc;
        }
    }
}

extern "C" void kernel_launch(void* const* d_in, const int* in_sizes, int n_in,
                              void* d_out, int out_size, void* d_ws, size_t ws_size,
                              hipStream_t stream) {
    const float* x  = (const float*)d_in[0];
    const float* w1 = (const float*)d_in[1];
    const float* w2 = (const float*)d_in[2];
    float* y = (float*)d_out;
    fused_kernel<<<dim3(NH, NI / ICHUNK), dim3(1024), 0, stream>>>(x, w1, w2, y);
}